// Round 17
// baseline (39.019 us; speedup 1.0000x reference)
//
#include <hip/hip_runtime.h>
#include <hip/hip_bf16.h>

#define N 4096
#define FIN 128
#define U0 16
#define H0 4
#define MAXD 128        // padded neighbor-list cap; P(deg>128), Binom(4096,0.01) ~ 0
#define NGEMM (N / 16)  // 256 gemm blocks
#define NATT0 (N / 8)   // 512 csr+attn0 blocks (8 rows each)
#define NATT1 (N / 16)  // 256 attn1 blocks (16 rows each)
#define FSTRIDE 32      // F row: h0[0..15], a2[16..19], pad to 128B line

// ---------------------------------------------------------------------------
// K1: gemm only.  h0/a2 -> fused F lines, a1, partS0 plain stores. (R15-proven)
// ---------------------------------------------------------------------------
__global__ void k1_gemm(const float* __restrict__ x, const float* __restrict__ w0,
                        const float* __restrict__ aw1, const float* __restrict__ aw2,
                        float* __restrict__ F, float* __restrict__ a1,
                        float* __restrict__ partS0) {
    __shared__ float xs[16][FIN + 1];
    __shared__ float ws[FIN][U0];
    __shared__ float hs[16][U0 + 1];
    const int t = threadIdx.x;
    const int r0 = blockIdx.x * 16;

    for (int k = t; k < FIN * U0; k += 256) ws[k / U0][k % U0] = w0[k];
    for (int k = t; k < 16 * FIN; k += 256)
        xs[k / FIN][k % FIN] = x[(size_t)(r0 + k / FIN) * FIN + (k % FIN)];
    __syncthreads();

    const int r = t / U0, u = t % U0;
    float acc = 0.f;
    #pragma unroll 8
    for (int k = 0; k < FIN; ++k) acc += xs[r][k] * ws[k][u];
    hs[r][u] = acc;
    F[(size_t)(r0 + r) * FSTRIDE + u] = acc;          // h0 part of the line
    __syncthreads();

    if (t < 16 * H0) {                 // 64 threads: (row, head)
        const int rr = t / H0, hh = t % H0;
        float s1 = 0.f, s2 = 0.f;
        #pragma unroll
        for (int u2 = 0; u2 < U0; ++u2) {
            float hv = hs[rr][u2];
            s1 += hv * aw1[u2 * H0 + hh];
            s2 += hv * aw2[u2 * H0 + hh];
        }
        a1[(r0 + rr) * H0 + hh] = s1;
        F[(size_t)(r0 + rr) * FSTRIDE + 16 + hh] = s2; // a2 part, same line
    } else if (t >= 128 && t < 144) {  // 16 threads: column partial, plain store
        const int d = t - 128;
        float s = 0.f;
        #pragma unroll
        for (int rr = 0; rr < 16; ++rr) s += hs[rr][d];
        partS0[blockIdx.x * 16 + d] = s;
    }
}

// ---------------------------------------------------------------------------
// K2: CSR-build + attn0 fused, 8 ROWS/BLOCK (512 wgs — wg-ramp lever).
// Stream 8 adj rows via 4 proven pair-passes into cls[8][*]; attn0 phase:
// wave wid handles rows {wid, wid+4} sequentially with the R12-proven
// vectorized F-line gather.  partS0 reduced per block (proven-free).
// ---------------------------------------------------------------------------
__global__ void csr_attn0(const float* __restrict__ adj, const float* __restrict__ F,
                          const float* __restrict__ a1, const float* __restrict__ partS0,
                          const float* __restrict__ w1,
                          int* __restrict__ deg, int* __restrict__ cols,
                          float* __restrict__ hp) {
    __shared__ int   cls[8][MAXD];    // 4 KB
    __shared__ int   wsum[4];
    __shared__ int   dgs[8];
    __shared__ float red[16][17];
    __shared__ float s0s[16];

    const int t = threadIdx.x;
    const int wid = t >> 6, lane = t & 63;
    const int i0 = blockIdx.x * 8;

    // ---- partS0 [256][16] -> s0s[16] ----
    {
        const int d = t & 15, ch = t >> 4;
        float s = 0.f;
        #pragma unroll
        for (int k = ch; k < 256; k += 16) s += partS0[k * 16 + d];
        red[ch][d] = s;
    }
    __syncthreads();
    if (t < 16) {
        float s2 = 0.f;
        #pragma unroll
        for (int k = 0; k < 16; ++k) s2 += red[k][t];
        s0s[t] = s2;
    }

    // ---- scan/compact one row from registers into LDS CSR ----
    auto proc = [&](int row, const float4* v) {
        int c = 0;
        #pragma unroll
        for (int p = 0; p < 4; ++p)
            c += (v[p].x != 0.f) + (v[p].y != 0.f) + (v[p].z != 0.f) + (v[p].w != 0.f);

        int sc = c;                          // inclusive wave scan (6 shfl steps)
        #pragma unroll
        for (int s = 1; s < 64; s <<= 1) {
            int u = __shfl_up(sc, s);
            if (lane >= s) sc += u;
        }
        __syncthreads();                     // prior wsum readers done (& s0s safe)
        if (lane == 63) wsum[wid] = sc;
        __syncthreads();
        int base = 0;
        #pragma unroll
        for (int w2 = 0; w2 < 4; ++w2)
            if (w2 < wid) base += wsum[w2];
        const int off = base + sc - c;
        if (t == 255) dgs[row] = min(base + sc, MAXD);

        int w = off;
        #pragma unroll
        for (int p = 0; p < 4; ++p) {
            const int j0 = (t + 256 * p) * 4;
            if (v[p].x != 0.f && w < MAXD) cls[row][w++] = j0;
            if (v[p].y != 0.f && w < MAXD) cls[row][w++] = j0 + 1;
            if (v[p].z != 0.f && w < MAXD) cls[row][w++] = j0 + 2;
            if (v[p].w != 0.f && w < MAXD) cls[row][w++] = j0 + 3;
        }
    };

    // ---- stream 8 adj rows (4 pair-passes) ----
    for (int pair = 0; pair < 4; ++pair) {
        const int rb = i0 + pair * 2;
        const float4* __restrict__ ar0 =
            reinterpret_cast<const float4*>(adj + (size_t)rb * N);
        const float4* __restrict__ ar1 =
            reinterpret_cast<const float4*>(adj + (size_t)(rb + 1) * N);
        float4 v0[4], v1[4];
        #pragma unroll
        for (int p = 0; p < 4; ++p) v0[p] = ar0[t + 256 * p];
        #pragma unroll
        for (int p = 0; p < 4; ++p) v1[p] = ar1[t + 256 * p];
        proc(pair * 2, v0);
        proc(pair * 2 + 1, v1);
    }
    __syncthreads();

    // ---- zero-pad cls tails; persist cols/deg for attn1 ----
    for (int k = t; k < 8 * MAXD; k += 256) {
        const int row = k >> 7, idx = k & 127;
        if (idx < dgs[row]) cols[(size_t)(i0 + row) * MAXD + idx] = cls[row][idx];
        else                cls[row][idx] = 0;
    }
    if (t < 8) deg[i0 + t] = dgs[t];
    __syncthreads();

    // ---- attn0: wave wid handles rows {wid, wid+4} (vectorized gather) ----
    const int q = lane >> 4, r = lane & 15;
    const int hh = r >> 2, dgc = r & 3;
    const float4 s0v = reinterpret_cast<const float4*>(s0s)[dgc];
    const float4 w1v = reinterpret_cast<const float4*>(w1)[r];

    #pragma unroll
    for (int half = 0; half < 2; ++half) {
        const int row = wid + half * 4;
        const int i = i0 + row;
        const int dg = dgs[row];
        const float a1v = a1[i * H0 + hh];

        float4 accn = make_float4(0.f, 0.f, 0.f, 0.f);
        float accd = 0.f;
        for (int kb = 0; kb < dg; kb += 8) {         // wave-uniform trip count
            const int kA = kb + q;
            const int kB = kb + 4 + q;
            const int jA = cls[row][kA < MAXD ? kA : 0];
            const int jB = cls[row][kB < MAXD ? kB : 0];
            const float msA = (kA < dg) ? 1.f : 0.f;
            const float msB = (kB < dg) ? 1.f : 0.f;
            const float* __restrict__ fA = F + (size_t)jA * FSTRIDE;
            const float* __restrict__ fB = F + (size_t)jB * FSTRIDE;
            const float4 hA = *reinterpret_cast<const float4*>(fA + dgc * 4);
            const float a2A = fA[16 + hh];
            const float4 hB = *reinterpret_cast<const float4*>(fB + dgc * 4);
            const float a2B = fB[16 + hh];

            float ccA = a1v + a2A;
            ccA = ccA > 0.f ? ccA : 0.f;
            const float eA = (__expf(ccA) - 1.f) * msA;
            accn.x = fmaf(eA, hA.x, accn.x);
            accn.y = fmaf(eA, hA.y, accn.y);
            accn.z = fmaf(eA, hA.z, accn.z);
            accn.w = fmaf(eA, hA.w, accn.w);
            accd += eA;

            float ccB = a1v + a2B;
            ccB = ccB > 0.f ? ccB : 0.f;
            const float eB = (__expf(ccB) - 1.f) * msB;
            accn.x = fmaf(eB, hB.x, accn.x);
            accn.y = fmaf(eB, hB.y, accn.y);
            accn.z = fmaf(eB, hB.z, accn.z);
            accn.w = fmaf(eB, hB.w, accn.w);
            accd += eB;
        }
        #pragma unroll
        for (int m = 16; m <= 32; m <<= 1) {
            accn.x += __shfl_xor(accn.x, m);
            accn.y += __shfl_xor(accn.y, m);
            accn.z += __shfl_xor(accn.z, m);
            accn.w += __shfl_xor(accn.w, m);
            accd   += __shfl_xor(accd, m);
        }
        const float inv = 1.f / (accd + (float)N);
        float ox = (accn.x + s0v.x) * inv; ox = ox > 0.f ? ox : 0.f;
        float oy = (accn.y + s0v.y) * inv; oy = oy > 0.f ? oy : 0.f;
        float oz = (accn.z + s0v.z) * inv; oz = oz > 0.f ? oz : 0.f;
        float ow = (accn.w + s0v.w) * inv; ow = ow > 0.f ? ow : 0.f;
        float pv = ox * w1v.x + oy * w1v.y + oz * w1v.z + ow * w1v.w;
        #pragma unroll
        for (int m = 1; m <= 8; m <<= 1) pv += __shfl_xor(pv, m);
        if (lane == 0) hp[i] = pv;
    }
}

// ---------------------------------------------------------------------------
// K3: layer-1 sparse attention + sigmoid, 16 ROWS/BLOCK (256 wgs).
// Stages all of hp (16 KB) into LDS; S1 free block-reduce; each wave does
// 4 rows sequentially (each row ~1 LDS-gather iteration).
// ---------------------------------------------------------------------------
__global__ void attn1(const float* __restrict__ hp,
                      const float* __restrict__ aw11, const float* __restrict__ aw21,
                      const int* __restrict__ deg, const int* __restrict__ cols,
                      float* __restrict__ out) {
    __shared__ float hps[N];          // 16 KB
    __shared__ int cls[16][MAXD];     // 8 KB
    __shared__ float s1red[4];
    const int t = threadIdx.x;
    const int w = t >> 6, lane = t & 63;
    const int i0 = blockIdx.x * 16;

    float s = 0.f;
    const float4* __restrict__ hp4 = reinterpret_cast<const float4*>(hp);
    #pragma unroll
    for (int k = t; k < N / 4; k += 256) {
        float4 v = hp4[k];
        reinterpret_cast<float4*>(hps)[k] = v;
        s += v.x + v.y + v.z + v.w;
    }
    for (int k = t; k < 16 * MAXD; k += 256)
        cls[k >> 7][k & 127] = cols[(size_t)(i0 + (k >> 7)) * MAXD + (k & 127)];

    #pragma unroll
    for (int o = 32; o; o >>= 1) s += __shfl_down(s, o);
    if (lane == 0) s1red[w] = s;
    __syncthreads();
    const float S1 = s1red[0] + s1red[1] + s1red[2] + s1red[3];

    const float w1v = aw11[0], w2v = aw21[0];
    #pragma unroll
    for (int rr = 0; rr < 4; ++rr) {
        const int row = w * 4 + rr;               // wave's rr-th row
        const int i = i0 + row;
        const float a1v = hps[i] * w1v;
        const int dg = deg[i];

        float accn = 0.f, accd = 0.f;
        for (int k = lane; k < dg; k += 64) {
            const int j = cls[row][k];
            const float hj = hps[j];
            float cc = a1v + hj * w2v;
            cc = cc > 0.f ? cc : 0.f;
            const float e = __expf(cc) - 1.f;
            accn = fmaf(e, hj, accn);
            accd += e;
        }
        #pragma unroll
        for (int o = 32; o; o >>= 1) {
            accn += __shfl_down(accn, o);
            accd += __shfl_down(accd, o);
        }
        if (lane == 0) {
            const float v = (accn + S1) / (accd + (float)N);
            out[i] = 1.f / (1.f + __expf(-v));
        }
    }
}

// ---------------------------------------------------------------------------
extern "C" void kernel_launch(void* const* d_in, const int* in_sizes, int n_in,
                              void* d_out, int out_size, void* d_ws, size_t ws_size,
                              hipStream_t stream) {
    const float* x    = (const float*)d_in[0];
    const float* adj  = (const float*)d_in[1];
    const float* w0   = (const float*)d_in[2];
    const float* aw10 = (const float*)d_in[3];
    const float* aw20 = (const float*)d_in[4];
    const float* w1   = (const float*)d_in[5];
    const float* aw11 = (const float*)d_in[6];
    const float* aw21 = (const float*)d_in[7];
    float* out = (float*)d_out;

    char* p = (char*)d_ws;
    auto alloc = [&](size_t bytes) {
        char* r = p;
        p += (bytes + 255) & ~(size_t)255;
        return r;
    };
    float* partS0 = (float*)alloc(NGEMM * 16 * 4);          // 16 KB
    float* F      = (float*)alloc((size_t)N * FSTRIDE * 4); // 512 KB fused h0+a2
    float* a1     = (float*)alloc((size_t)N * H0 * 4);
    float* hp     = (float*)alloc((size_t)N * 4);
    int*   deg    = (int*)alloc((size_t)N * 4);
    int*   cols   = (int*)alloc((size_t)N * MAXD * 4);

    k1_gemm<<<NGEMM, 256, 0, stream>>>(x, w0, aw10, aw20, F, a1, partS0);
    csr_attn0<<<NATT0, 256, 0, stream>>>(adj, F, a1, partS0, w1, deg, cols, hp);
    attn1<<<NATT1, 256, 0, stream>>>(hp, aw11, aw21, deg, cols, out);
}

// Round 18
// 34.694 us; speedup vs baseline: 1.1247x; 1.1247x over previous
//
#include <hip/hip_runtime.h>
#include <hip/hip_bf16.h>

#define N 4096
#define FIN 128
#define U0 16
#define H0 4
#define MAXD 128        // padded neighbor-list cap; P(deg>128), Binom(4096,0.01) ~ 0
#define NGEMM (N / 16)  // 256 gemm blocks
#define NATT  (N / 4)   // 1024 csr+attn0 blocks (4 rows each)
#define FSTRIDE 32      // F row: h0[0..15], a2[16..19], pad to 128B line

// ---------------------------------------------------------------------------
// K1: gemm only (tiny, fast-draining).  h0/a2 -> fused F lines, a1,
// partS0 plain stores (no atomics -> no memset node anywhere).
// ---------------------------------------------------------------------------
__global__ void k1_gemm(const float* __restrict__ x, const float* __restrict__ w0,
                        const float* __restrict__ aw1, const float* __restrict__ aw2,
                        float* __restrict__ F, float* __restrict__ a1,
                        float* __restrict__ partS0) {
    __shared__ float xs[16][FIN + 1];
    __shared__ float ws[FIN][U0];
    __shared__ float hs[16][U0 + 1];
    const int t = threadIdx.x;
    const int r0 = blockIdx.x * 16;

    for (int k = t; k < FIN * U0; k += 256) ws[k / U0][k % U0] = w0[k];
    for (int k = t; k < 16 * FIN; k += 256)
        xs[k / FIN][k % FIN] = x[(size_t)(r0 + k / FIN) * FIN + (k % FIN)];
    __syncthreads();

    const int r = t / U0, u = t % U0;
    float acc = 0.f;
    #pragma unroll 8
    for (int k = 0; k < FIN; ++k) acc += xs[r][k] * ws[k][u];
    hs[r][u] = acc;
    F[(size_t)(r0 + r) * FSTRIDE + u] = acc;          // h0 part of the line
    __syncthreads();

    if (t < 16 * H0) {                 // 64 threads: (row, head)
        const int rr = t / H0, hh = t % H0;
        float s1 = 0.f, s2 = 0.f;
        #pragma unroll
        for (int u2 = 0; u2 < U0; ++u2) {
            float hv = hs[rr][u2];
            s1 += hv * aw1[u2 * H0 + hh];
            s2 += hv * aw2[u2 * H0 + hh];
        }
        a1[(r0 + rr) * H0 + hh] = s1;
        F[(size_t)(r0 + rr) * FSTRIDE + 16 + hh] = s2; // a2 part, same line
    } else if (t >= 128 && t < 144) {  // 16 threads: column partial, plain store
        const int d = t - 128;
        float s = 0.f;
        #pragma unroll
        for (int rr = 0; rr < 16; ++rr) s += hs[rr][d];
        partS0[blockIdx.x * 16 + d] = s;
    }
}

// ---------------------------------------------------------------------------
// K2: CSR-build + attn0 fused (4 rows/block).  The block streams its 4 adj
// rows into an LDS CSR and the vectorized gather consumes it IN-LDS (no cols
// read-back).  cols/deg persisted only for attn1.  partS0 reduced per block.
// ---------------------------------------------------------------------------
__global__ void csr_attn0(const float* __restrict__ adj, const float* __restrict__ F,
                          const float* __restrict__ a1, const float* __restrict__ partS0,
                          const float* __restrict__ w1,
                          int* __restrict__ deg, int* __restrict__ cols,
                          float* __restrict__ hp) {
    __shared__ int   cls[4][MAXD];    // 2 KB
    __shared__ int   wsum[4];
    __shared__ int   dgs[4];
    __shared__ float red[16][17];
    __shared__ float s0s[16];

    const int t = threadIdx.x;
    const int wid = t >> 6, lane = t & 63;
    const int i0 = blockIdx.x * 4;

    // ---- partS0 [256][16] -> s0s[16] (L2-hot, ~1us) ----
    {
        const int d = t & 15, ch = t >> 4;
        float s = 0.f;
        #pragma unroll
        for (int k = ch; k < 256; k += 16) s += partS0[k * 16 + d];
        red[ch][d] = s;
    }
    __syncthreads();
    if (t < 16) {
        float s2 = 0.f;
        #pragma unroll
        for (int k = 0; k < 16; ++k) s2 += red[k][t];
        s0s[t] = s2;
    }

    // ---- stream 4 adj rows -> LDS CSR (2 passes of 2 rows) ----
    for (int pair = 0; pair < 2; ++pair) {
        const int rb = i0 + pair * 2;
        const float4* __restrict__ ar0 =
            reinterpret_cast<const float4*>(adj + (size_t)rb * N);
        const float4* __restrict__ ar1 =
            reinterpret_cast<const float4*>(adj + (size_t)(rb + 1) * N);
        float4 v0[4], v1[4];
        #pragma unroll
        for (int p = 0; p < 4; ++p) v0[p] = ar0[t + 256 * p];
        #pragma unroll
        for (int p = 0; p < 4; ++p) v1[p] = ar1[t + 256 * p];

        #pragma unroll
        for (int rr = 0; rr < 2; ++rr) {
            const float4* v = rr ? v1 : v0;
            const int row = pair * 2 + rr;
            int c = 0;
            #pragma unroll
            for (int p = 0; p < 4; ++p)
                c += (v[p].x != 0.f) + (v[p].y != 0.f) + (v[p].z != 0.f) + (v[p].w != 0.f);

            int sc = c;                      // inclusive wave scan (6 shfl steps)
            #pragma unroll
            for (int s = 1; s < 64; s <<= 1) {
                int u = __shfl_up(sc, s);
                if (lane >= s) sc += u;
            }
            __syncthreads();                 // wsum (and s0s on first iter) safe
            if (lane == 63) wsum[wid] = sc;
            __syncthreads();
            int base = 0;
            #pragma unroll
            for (int w2 = 0; w2 < 4; ++w2)
                if (w2 < wid) base += wsum[w2];
            const int off = base + sc - c;
            if (t == 255) dgs[row] = min(base + sc, MAXD);

            int w = off;                     // compact into LDS
            #pragma unroll
            for (int p = 0; p < 4; ++p) {
                const int j0 = (t + 256 * p) * 4;
                if (v[p].x != 0.f && w < MAXD) cls[row][w++] = j0;
                if (v[p].y != 0.f && w < MAXD) cls[row][w++] = j0 + 1;
                if (v[p].z != 0.f && w < MAXD) cls[row][w++] = j0 + 2;
                if (v[p].w != 0.f && w < MAXD) cls[row][w++] = j0 + 3;
            }
        }
    }
    __syncthreads();

    // ---- zero-pad cls tails (masked gather lanes must index valid rows) ----
    // and persist cols/deg for attn1 (stores are fire-and-forget)
    for (int k = t; k < 4 * MAXD; k += 256) {
        const int row = k >> 7, idx = k & 127;
        if (idx < dgs[row]) cols[(size_t)(i0 + row) * MAXD + idx] = cls[row][idx];
        else                cls[row][idx] = 0;
    }
    if (t < 4) deg[i0 + t] = dgs[t];
    __syncthreads();

    // ---- attn0: one wave per row, vectorized F-line gather (R12-proven) ----
    const int i = i0 + wid;
    const int dg = dgs[wid];
    const int q = lane >> 4, r = lane & 15;
    const int hh = r >> 2, dgc = r & 3;
    const float a1v = a1[i * H0 + hh];

    float4 accn = make_float4(0.f, 0.f, 0.f, 0.f);
    float accd = 0.f;
    for (int kb = 0; kb < dg; kb += 8) {             // wave-uniform trip count
        const int kA = kb + q;
        const int kB = kb + 4 + q;
        const int jA = cls[wid][kA < MAXD ? kA : 0];
        const int jB = cls[wid][kB < MAXD ? kB : 0];
        const float msA = (kA < dg) ? 1.f : 0.f;
        const float msB = (kB < dg) ? 1.f : 0.f;
        const float* __restrict__ fA = F + (size_t)jA * FSTRIDE;
        const float* __restrict__ fB = F + (size_t)jB * FSTRIDE;
        const float4 hA = *reinterpret_cast<const float4*>(fA + dgc * 4);
        const float a2A = fA[16 + hh];
        const float4 hB = *reinterpret_cast<const float4*>(fB + dgc * 4);
        const float a2B = fB[16 + hh];

        float ccA = a1v + a2A;
        ccA = ccA > 0.f ? ccA : 0.f;
        const float eA = (__expf(ccA) - 1.f) * msA;
        accn.x = fmaf(eA, hA.x, accn.x);
        accn.y = fmaf(eA, hA.y, accn.y);
        accn.z = fmaf(eA, hA.z, accn.z);
        accn.w = fmaf(eA, hA.w, accn.w);
        accd += eA;

        float ccB = a1v + a2B;
        ccB = ccB > 0.f ? ccB : 0.f;
        const float eB = (__expf(ccB) - 1.f) * msB;
        accn.x = fmaf(eB, hB.x, accn.x);
        accn.y = fmaf(eB, hB.y, accn.y);
        accn.z = fmaf(eB, hB.z, accn.z);
        accn.w = fmaf(eB, hB.w, accn.w);
        accd += eB;
    }
    #pragma unroll
    for (int m = 16; m <= 32; m <<= 1) {
        accn.x += __shfl_xor(accn.x, m);
        accn.y += __shfl_xor(accn.y, m);
        accn.z += __shfl_xor(accn.z, m);
        accn.w += __shfl_xor(accn.w, m);
        accd   += __shfl_xor(accd, m);
    }
    const float4 s0v = reinterpret_cast<const float4*>(s0s)[dgc];
    const float4 w1v = reinterpret_cast<const float4*>(w1)[r];
    const float inv = 1.f / (accd + (float)N);
    float ox = (accn.x + s0v.x) * inv; ox = ox > 0.f ? ox : 0.f;
    float oy = (accn.y + s0v.y) * inv; oy = oy > 0.f ? oy : 0.f;
    float oz = (accn.z + s0v.z) * inv; oz = oz > 0.f ? oz : 0.f;
    float ow = (accn.w + s0v.w) * inv; ow = ow > 0.f ? ow : 0.f;
    float pv = ox * w1v.x + oy * w1v.y + oz * w1v.z + ow * w1v.w;
    #pragma unroll
    for (int m = 1; m <= 8; m <<= 1) pv += __shfl_xor(pv, m);
    if (lane == 0) hp[i] = pv;
}

// ---------------------------------------------------------------------------
// K3: layer-1 sparse attention + sigmoid -> out [4096].  (R12-proven)
// Stages all of hp (16 KB) into LDS; S1 free block-reduce; LDS gather.
// ---------------------------------------------------------------------------
__global__ void attn1(const float* __restrict__ hp,
                      const float* __restrict__ aw11, const float* __restrict__ aw21,
                      const int* __restrict__ deg, const int* __restrict__ cols,
                      float* __restrict__ out) {
    __shared__ float hps[N];          // 16 KB
    __shared__ int cls[4][MAXD];      // 2 KB
    __shared__ float s1red[4];
    const int t = threadIdx.x;
    const int w = t >> 6, lane = t & 63;
    const int i0 = blockIdx.x * 4;

    float s = 0.f;
    const float4* __restrict__ hp4 = reinterpret_cast<const float4*>(hp);
    #pragma unroll
    for (int k = t; k < N / 4; k += 256) {
        float4 v = hp4[k];
        reinterpret_cast<float4*>(hps)[k] = v;
        s += v.x + v.y + v.z + v.w;
    }
    for (int k = t; k < 4 * MAXD; k += 256)
        cls[k >> 7][k & 127] = cols[(size_t)(i0 + (k >> 7)) * MAXD + (k & 127)];

    #pragma unroll
    for (int o = 32; o; o >>= 1) s += __shfl_down(s, o);
    if (lane == 0) s1red[w] = s;
    __syncthreads();
    const float S1 = s1red[0] + s1red[1] + s1red[2] + s1red[3];

    const int i = i0 + w;
    const float w1v = aw11[0], w2v = aw21[0];
    const float a1v = hps[i] * w1v;
    const int dg = deg[i];

    float accn = 0.f, accd = 0.f;
    for (int k = lane; k < dg; k += 64) {
        const int j = cls[w][k];
        const float hj = hps[j];
        float cc = a1v + hj * w2v;
        cc = cc > 0.f ? cc : 0.f;
        const float e = __expf(cc) - 1.f;
        accn = fmaf(e, hj, accn);
        accd += e;
    }
    #pragma unroll
    for (int o = 32; o; o >>= 1) {
        accn += __shfl_down(accn, o);
        accd += __shfl_down(accd, o);
    }
    if (lane == 0) {
        const float v = (accn + S1) / (accd + (float)N);
        out[i] = 1.f / (1.f + __expf(-v));
    }
}

// ---------------------------------------------------------------------------
extern "C" void kernel_launch(void* const* d_in, const int* in_sizes, int n_in,
                              void* d_out, int out_size, void* d_ws, size_t ws_size,
                              hipStream_t stream) {
    const float* x    = (const float*)d_in[0];
    const float* adj  = (const float*)d_in[1];
    const float* w0   = (const float*)d_in[2];
    const float* aw10 = (const float*)d_in[3];
    const float* aw20 = (const float*)d_in[4];
    const float* w1   = (const float*)d_in[5];
    const float* aw11 = (const float*)d_in[6];
    const float* aw21 = (const float*)d_in[7];
    float* out = (float*)d_out;

    char* p = (char*)d_ws;
    auto alloc = [&](size_t bytes) {
        char* r = p;
        p += (bytes + 255) & ~(size_t)255;
        return r;
    };
    float* partS0 = (float*)alloc(NGEMM * 16 * 4);          // 16 KB
    float* F      = (float*)alloc((size_t)N * FSTRIDE * 4); // 512 KB fused h0+a2
    float* a1     = (float*)alloc((size_t)N * H0 * 4);
    float* hp     = (float*)alloc((size_t)N * 4);
    int*   deg    = (int*)alloc((size_t)N * 4);
    int*   cols   = (int*)alloc((size_t)N * MAXD * 4);

    k1_gemm<<<NGEMM, 256, 0, stream>>>(x, w0, aw10, aw20, F, a1, partS0);
    csr_attn0<<<NATT, 256, 0, stream>>>(adj, F, a1, partS0, w1, deg, cols, hp);
    attn1<<<NATT, 256, 0, stream>>>(hp, aw11, aw21, deg, cols, out);
}